// Round 2
// baseline (163.348 us; speedup 1.0000x reference)
//
#include <hip/hip_runtime.h>
#include <hip/hip_bf16.h>

// Embedding gather: out[i, :] = weight[idx[i], :]
// idx: [32768] int32, weight: [50257, 512] fp32, out: [32768, 512] fp32.
//
// Mapping: one wave (64 lanes) handles 4 consecutive rows (4 x 512 floats =
// 8 KiB contiguous output). Indices are wave-uniform -> readfirstlane forces
// them into SGPRs, so the 8 gather loads per lane are saddr-form with full
// ILP (128 B/lane in flight). This attacks the R0 latency bound (2-deep
// dependent chain with 16 B payload/thread ran at only ~0.8 TB/s).

#define EMBED_F4  128              // 512 floats / 4
#define N_IDX     (8 * 4096)       // 32768 rows
#define ROWS_PER_WAVE 4
#define N_WAVES   (N_IDX / ROWS_PER_WAVE)   // 8192 waves

__global__ __launch_bounds__(256) void Embedding_60327110640045_kernel(
    const int* __restrict__ idx,
    const float4* __restrict__ weight,   // [50257 * 128] float4
    float4* __restrict__ out)            // [32768 * 128] float4
{
    const int gtid = blockIdx.x * blockDim.x + threadIdx.x;
    const int wave = gtid >> 6;
    const int lane = threadIdx.x & 63;

    // One 16B load fetches this wave's 4 indices (wave-uniform address
    // content; per-lane load then broadcast via readfirstlane).
    const int4 rows4 = ((const int4*)idx)[wave];
    const int r0 = __builtin_amdgcn_readfirstlane(rows4.x);
    const int r1 = __builtin_amdgcn_readfirstlane(rows4.y);
    const int r2 = __builtin_amdgcn_readfirstlane(rows4.z);
    const int r3 = __builtin_amdgcn_readfirstlane(rows4.w);

    const float4* __restrict__ s0 = weight + (size_t)r0 * EMBED_F4;
    const float4* __restrict__ s1 = weight + (size_t)r1 * EMBED_F4;
    const float4* __restrict__ s2 = weight + (size_t)r2 * EMBED_F4;
    const float4* __restrict__ s3 = weight + (size_t)r3 * EMBED_F4;

    // 8 independent 16B loads per lane (2 per row), all issued before any use.
    float4 a0 = s0[lane];
    float4 a1 = s0[lane + 64];
    float4 b0 = s1[lane];
    float4 b1 = s1[lane + 64];
    float4 c0 = s2[lane];
    float4 c1 = s2[lane + 64];
    float4 d0 = s3[lane];
    float4 d1 = s3[lane + 64];

    float4* __restrict__ dst = out + (size_t)wave * (ROWS_PER_WAVE * EMBED_F4);
    dst[lane]       = a0;
    dst[lane + 64]  = a1;
    dst[lane + 128] = b0;
    dst[lane + 192] = b1;
    dst[lane + 256] = c0;
    dst[lane + 320] = c1;
    dst[lane + 384] = d0;
    dst[lane + 448] = d1;
}

extern "C" void kernel_launch(void* const* d_in, const int* in_sizes, int n_in,
                              void* d_out, int out_size, void* d_ws, size_t ws_size,
                              hipStream_t stream) {
    const int*    idx    = (const int*)d_in[0];
    const float4* weight = (const float4*)d_in[1];
    float4*       out    = (float4*)d_out;

    const int block = 256;                       // 4 waves/block
    const int grid  = N_WAVES * 64 / block;      // 2048 blocks
    Embedding_60327110640045_kernel<<<grid, block, 0, stream>>>(idx, weight, out);
}